// Round 8
// baseline (166.143 us; speedup 1.0000x reference)
//
#include <hip/hip_runtime.h>
#include <math.h>

// Whiten: per-(b,c) mean/std over 224x224 fp32 slices. B*C = 2048 slices.
// Floor: 411 MB read + 411 MB write @ ~6.3 TB/s ~= 131 us. Best so far:
// R1 (simple register staging, 2048 one-shot blocks) = 156.6 us; the 26 us
// gap is phase serialization (reads drain -> reduce -> stores -> retire).
//
// R8: persistent blocks (256 x 1024 thr, 8 slices each) with store/load
// overlap at R1's EXACT register budget (52 data VGPR, fixed-role buffers,
// no rotation -- R6's 3-buffer rotation cost 84+ and lost).
// Per slice: acc -> butterfly -> raw lgkm-only barrier (prefetched loads
// stay in flight; wred parity-buffered so one barrier/slice is race-free)
// -> broadcast stats -> store main; ISSUE main(s+1); store pre;
// ISSUE pre(s+1). ISA: vmcnt for a store completes when data is read out
// of the VGPR (not on HBM writeback), so loads into just-stored registers
// pay only a reg-read wait -- next-slice reads stream during this slice's
// store-drain window. Issue order (main,pre) == accumulate order, so
// loop-top waitcnts are incremental rather than a full drain.
// #pragma unroll 1 keeps iterations separate (no cross-iteration register
// pressure blowup).

namespace {
constexpr int   kHW       = 224 * 224;              // 50176
constexpr int   kHW4      = kHW / 4;                // 12544 float4 / slice
constexpr int   kThreads  = 1024;
constexpr int   kWaves    = kThreads / 64;          // 16
constexpr int   kPerBlock = 8;
constexpr int   kBlocks   = (64 * 32) / kPerBlock;  // 256
constexpr int   kPreRows  = 5;                      // rows 0..4 (full)
constexpr int   kMainRows = 7;                      // rows 5..11 (full)
constexpr int   kQOff     = 12 * kThreads;          // 12288, quarter row
constexpr int   kQCnt     = kHW4 - kQOff;           // 256 (tid<256)
constexpr float kMinDev   = 1.0f / 224.0f;          // 1/sqrt(H*W)

typedef float vfloat4 __attribute__((ext_vector_type(4)));
}

__global__ __launch_bounds__(kThreads, 4)   // cap 128 VGPR, 1 block/CU
void whiten_overlap(const float* __restrict__ x, float* __restrict__ y) {
    __shared__ float2 wred[2][kWaves];      // parity-double-buffered stats

    const int  tid  = threadIdx.x;
    const int  wid  = tid >> 6;
    const int  lane = tid & 63;
    const bool q    = (tid < kQCnt);
    const size_t base = (size_t)blockIdx.x * kPerBlock * kHW4;
    const vfloat4* __restrict__ xs = reinterpret_cast<const vfloat4*>(x) + base;
    vfloat4* __restrict__ ys       = reinterpret_cast<vfloat4*>(y) + base;

    vfloat4 mn[kMainRows + 1];   // rows 5..11 + quarter row (32 VGPR)
    vfloat4 pre[kPreRows];       // rows 0..4                 (20 VGPR)

    auto issueMain = [&](int s) {
        const vfloat4* __restrict__ p = xs + (size_t)s * kHW4;
#pragma unroll
        for (int i = 0; i < kMainRows; ++i)
            mn[i] = p[(kPreRows + i) * kThreads + tid];
        if (q) mn[kMainRows] = p[kQOff + tid];
    };
    auto issuePre = [&](int s) {
        const vfloat4* __restrict__ p = xs + (size_t)s * kHW4;
#pragma unroll
        for (int i = 0; i < kPreRows; ++i) pre[i] = p[i * kThreads + tid];
    };
    auto acc1 = [&](const vfloat4& v, float& sum, float& ssq) {
        sum += v.x + v.y + v.z + v.w;
        ssq = fmaf(v.x, v.x, ssq);
        ssq = fmaf(v.y, v.y, ssq);
        ssq = fmaf(v.z, v.z, ssq);
        ssq = fmaf(v.w, v.w, ssq);
    };
    auto norm1 = [&](const vfloat4& v, float mean, float rcp) {
        vfloat4 o;
        o.x = (v.x - mean) * rcp;
        o.y = (v.y - mean) * rcp;
        o.z = (v.z - mean) * rcp;
        o.w = (v.w - mean) * rcp;
        return o;
    };

    auto step = [&](int s, bool prefetchNext) {
        // ---- accumulate in ISSUE order (main first, then pre) ----
        float sum = 0.f, ssq = 0.f;
#pragma unroll
        for (int i = 0; i < kMainRows; ++i) acc1(mn[i], sum, ssq);
        if (q) acc1(mn[kMainRows], sum, ssq);
#pragma unroll
        for (int i = 0; i < kPreRows; ++i) acc1(pre[i], sum, ssq);

        // ---- wave64 butterfly ----
#pragma unroll
        for (int off = 32; off >= 1; off >>= 1) {
            sum += __shfl_down(sum, off, 64);
            ssq += __shfl_down(ssq, off, 64);
        }
        if (lane == 0) wred[s & 1][wid] = make_float2(sum, ssq);
        // LDS-only barrier: never drain vmcnt in the loop.
        asm volatile("s_waitcnt lgkmcnt(0)\n\ts_barrier" ::: "memory");

        // ---- broadcast stats (all threads reduce 16 entries) ----
        float S = 0.f, SS = 0.f;
#pragma unroll
        for (int i = 0; i < kWaves; ++i) {
            S += wred[s & 1][i].x;
            SS += wred[s & 1][i].y;
        }
        const float mean = S * (1.0f / kHW);
        float var = (SS - S * mean) * (1.0f / (kHW - 1));
        var = fmaxf(var, 0.f);
        const float rcp = 1.0f / fmaxf(sqrtf(var), kMinDev);

        // ---- store main(s); refill main with slice s+1 ----
        vfloat4* __restrict__ p = ys + (size_t)s * kHW4;
#pragma unroll
        for (int i = 0; i < kMainRows; ++i)
            p[(kPreRows + i) * kThreads + tid] = norm1(mn[i], mean, rcp);
        if (q) p[kQOff + tid] = norm1(mn[kMainRows], mean, rcp);
        if (prefetchNext) issueMain(s + 1);   // WAR on stores = cheap
                                              // (vmcnt store = reg-read done)
        // ---- store pre(s); refill pre with slice s+1 ----
#pragma unroll
        for (int i = 0; i < kPreRows; ++i)
            p[i * kThreads + tid] = norm1(pre[i], mean, rcp);
        if (prefetchNext) issuePre(s + 1);
    };

    // prologue: issue order main-then-pre (matches steady state)
    issueMain(0);
    issuePre(0);
#pragma unroll 1
    for (int s = 0; s < kPerBlock - 1; ++s) step(s, true);
    step(kPerBlock - 1, false);
}

extern "C" void kernel_launch(void* const* d_in, const int* in_sizes, int n_in,
                              void* d_out, int out_size, void* d_ws, size_t ws_size,
                              hipStream_t stream) {
    (void)in_sizes; (void)n_in; (void)d_ws; (void)ws_size; (void)out_size;
    const float* x = reinterpret_cast<const float*>(d_in[0]);
    float* y = reinterpret_cast<float*>(d_out);
    whiten_overlap<<<kBlocks, kThreads, 0, stream>>>(x, y);
}

// Round 9
// 156.588 us; speedup vs baseline: 1.0610x; 1.0610x over previous
//
#include <hip/hip_runtime.h>
#include <math.h>

// Whiten: per-(b,c) mean/std over 224x224 fp32 slices. B*C = 2048 slices.
// Floor: 411 MB read + 411 MB write @ ~6.3 TB/s ~= 131 us.
//
// R9 = R1's winning skeleton (phased: read-all -> reduce -> write-all;
// one-shot 1024-thread block per slice; 13 float4 staged in registers;
// NO read/write overlap -- R6/R7/R8 proved concurrent read+write streams
// settle at ~4.95 TB/s vs R1's phased 5.25 TB/s) with ONE change:
// the stats critical path is de-serialized.
//   R1: butterfly -> barrier -> tid0 walks 16 LDS entries (serial ~400cyc)
//       -> barrier -> broadcast.           (2 barriers + serial chain)
//   R9: 2-way split accumulator chains, __shfl_xor butterfly, lane0 writes
//       float2, ONE __syncthreads (vmcnt already 0: all loads consumed),
//       then ALL threads broadcast-read the 16 entries in parallel.
// Everything else is byte-identical to R1's structure.

namespace {
constexpr int kHW      = 224 * 224;                 // 50176
constexpr int kHW4     = kHW / 4;                   // 12544 float4 / slice
constexpr int kThreads = 1024;
constexpr int kIt      = kHW4 / kThreads;           // 12
constexpr int kExtra   = kHW4 - kIt * kThreads;     // 256 tail float4
constexpr int kSlices  = 64 * 32;                   // 2048
constexpr int kWaves   = kThreads / 64;             // 16
constexpr float kMinDev = 1.0f / 224.0f;            // 1/sqrt(H*W)

typedef float vfloat4 __attribute__((ext_vector_type(4)));
}

__global__ __launch_bounds__(kThreads, 1)
void whiten_r9(const float* __restrict__ x, float* __restrict__ y) {
    __shared__ float2 wred[kWaves];

    const int tid  = threadIdx.x;
    const int wid  = tid >> 6;
    const int lane = tid & 63;
    const bool extra = (tid < kExtra);
    const size_t base = (size_t)blockIdx.x * kHW4;
    const vfloat4* __restrict__ xs = reinterpret_cast<const vfloat4*>(x) + base;
    vfloat4* __restrict__ ys       = reinterpret_cast<vfloat4*>(y) + base;

    // ---- phase 1: read entire slice into registers ----
    vfloat4 v[kIt];
    vfloat4 ve = {0.f, 0.f, 0.f, 0.f};
#pragma unroll
    for (int i = 0; i < kIt; ++i) v[i] = xs[tid + i * kThreads];
    if (extra) ve = xs[kIt * kThreads + tid];

    // ---- per-thread partials, 2-way split chains (shorter dep latency) ----
    float s0 = 0.f, s1 = 0.f, q0 = 0.f, q1 = 0.f;
#pragma unroll
    for (int i = 0; i < kIt; ++i) {
        s0 += v[i].x + v[i].y;
        s1 += v[i].z + v[i].w;
        q0 = fmaf(v[i].x, v[i].x, q0);
        q1 = fmaf(v[i].y, v[i].y, q1);
        q0 = fmaf(v[i].z, v[i].z, q0);
        q1 = fmaf(v[i].w, v[i].w, q1);
    }
    s0 += ve.x + ve.y;
    s1 += ve.z + ve.w;
    q0 = fmaf(ve.x, ve.x, q0);
    q1 = fmaf(ve.y, ve.y, q1);
    q0 = fmaf(ve.z, ve.z, q0);
    q1 = fmaf(ve.w, ve.w, q1);
    float sum = s0 + s1;
    float ssq = q0 + q1;

    // ---- wave64 xor-butterfly ----
#pragma unroll
    for (int off = 32; off >= 1; off >>= 1) {
        sum += __shfl_xor(sum, off, 64);
        ssq += __shfl_xor(ssq, off, 64);
    }
    if (lane == 0) wred[wid] = make_float2(sum, ssq);
    __syncthreads();   // single barrier; vmcnt already 0 (loads consumed)

    // ---- all threads broadcast-reduce the 16 wave entries ----
    float S = 0.f, SS = 0.f;
#pragma unroll
    for (int i = 0; i < kWaves; ++i) { S += wred[i].x; SS += wred[i].y; }
    const float mean = S * (1.0f / kHW);
    float var = (SS - S * mean) * (1.0f / (kHW - 1));
    var = fmaxf(var, 0.f);
    const float rcp = 1.0f / fmaxf(sqrtf(var), kMinDev);

    // ---- phase 2: normalize + store from registers ----
#pragma unroll
    for (int i = 0; i < kIt; ++i) {
        vfloat4 o;
        o.x = (v[i].x - mean) * rcp;
        o.y = (v[i].y - mean) * rcp;
        o.z = (v[i].z - mean) * rcp;
        o.w = (v[i].w - mean) * rcp;
        ys[tid + i * kThreads] = o;
    }
    if (extra) {
        vfloat4 o;
        o.x = (ve.x - mean) * rcp;
        o.y = (ve.y - mean) * rcp;
        o.z = (ve.z - mean) * rcp;
        o.w = (ve.w - mean) * rcp;
        ys[kIt * kThreads + tid] = o;
    }
}

extern "C" void kernel_launch(void* const* d_in, const int* in_sizes, int n_in,
                              void* d_out, int out_size, void* d_ws, size_t ws_size,
                              hipStream_t stream) {
    (void)in_sizes; (void)n_in; (void)d_ws; (void)ws_size; (void)out_size;
    const float* x = reinterpret_cast<const float*>(d_in[0]);
    float* y = reinterpret_cast<float*>(d_out);
    whiten_r9<<<kSlices, kThreads, 0, stream>>>(x, y);
}

// Round 10
// 140.147 us; speedup vs baseline: 1.1855x; 1.1173x over previous
//
#include <hip/hip_runtime.h>
#include <math.h>

// Whiten: per-(b,c) mean/std over 224x224 fp32 slices. B*C = 2048 slices.
// Floor: 411 MB read + 411 MB write @ ~6.3 TB/s ~= 131 us.
//
// R10 = R9's skeleton (the only structure that works: phased read-all ->
// reduce -> write-all, one-shot 1024-thread block per slice, 13 float4 in
// registers; overlap/co-residency/pipelining all measured worse) with ONE
// change: both memory streams are NONTEMPORAL (no L2/L3 allocate).
//   - x is read exactly once  -> caching it is pure pollution.
//   - y is written exactly once -> write-allocate churns the 4MB XCD L2
//     against the next round's read burst.
// nt load/store emit the `nt` cache flag; traffic is unchanged, only the
// allocation policy. If this is neutral, the remaining ~16% over the copy
// ceiling is structural phase-tail latency and R9 is the roofline kernel.

namespace {
constexpr int kHW      = 224 * 224;                 // 50176
constexpr int kHW4     = kHW / 4;                   // 12544 float4 / slice
constexpr int kThreads = 1024;
constexpr int kIt      = kHW4 / kThreads;           // 12
constexpr int kExtra   = kHW4 - kIt * kThreads;     // 256 tail float4
constexpr int kSlices  = 64 * 32;                   // 2048
constexpr int kWaves   = kThreads / 64;             // 16
constexpr float kMinDev = 1.0f / 224.0f;            // 1/sqrt(H*W)

typedef float vfloat4 __attribute__((ext_vector_type(4)));
}

__global__ __launch_bounds__(kThreads, 1)
void whiten_r10(const float* __restrict__ x, float* __restrict__ y) {
    __shared__ float2 wred[kWaves];

    const int tid  = threadIdx.x;
    const int wid  = tid >> 6;
    const int lane = tid & 63;
    const bool extra = (tid < kExtra);
    const size_t base = (size_t)blockIdx.x * kHW4;
    const vfloat4* __restrict__ xs = reinterpret_cast<const vfloat4*>(x) + base;
    vfloat4* __restrict__ ys       = reinterpret_cast<vfloat4*>(y) + base;

    // ---- phase 1: read entire slice into registers (nontemporal) ----
    vfloat4 v[kIt];
    vfloat4 ve = {0.f, 0.f, 0.f, 0.f};
#pragma unroll
    for (int i = 0; i < kIt; ++i)
        v[i] = __builtin_nontemporal_load(&xs[tid + i * kThreads]);
    if (extra) ve = __builtin_nontemporal_load(&xs[kIt * kThreads + tid]);

    // ---- per-thread partials, 2-way split chains ----
    float s0 = 0.f, s1 = 0.f, q0 = 0.f, q1 = 0.f;
#pragma unroll
    for (int i = 0; i < kIt; ++i) {
        s0 += v[i].x + v[i].y;
        s1 += v[i].z + v[i].w;
        q0 = fmaf(v[i].x, v[i].x, q0);
        q1 = fmaf(v[i].y, v[i].y, q1);
        q0 = fmaf(v[i].z, v[i].z, q0);
        q1 = fmaf(v[i].w, v[i].w, q1);
    }
    s0 += ve.x + ve.y;
    s1 += ve.z + ve.w;
    q0 = fmaf(ve.x, ve.x, q0);
    q1 = fmaf(ve.y, ve.y, q1);
    q0 = fmaf(ve.z, ve.z, q0);
    q1 = fmaf(ve.w, ve.w, q1);
    float sum = s0 + s1;
    float ssq = q0 + q1;

    // ---- wave64 xor-butterfly ----
#pragma unroll
    for (int off = 32; off >= 1; off >>= 1) {
        sum += __shfl_xor(sum, off, 64);
        ssq += __shfl_xor(ssq, off, 64);
    }
    if (lane == 0) wred[wid] = make_float2(sum, ssq);
    __syncthreads();   // single barrier; vmcnt already 0 (loads consumed)

    // ---- all threads broadcast-reduce the 16 wave entries ----
    float S = 0.f, SS = 0.f;
#pragma unroll
    for (int i = 0; i < kWaves; ++i) { S += wred[i].x; SS += wred[i].y; }
    const float mean = S * (1.0f / kHW);
    float var = (SS - S * mean) * (1.0f / (kHW - 1));
    var = fmaxf(var, 0.f);
    const float rcp = 1.0f / fmaxf(sqrtf(var), kMinDev);

    // ---- phase 2: normalize + store from registers (nontemporal) ----
#pragma unroll
    for (int i = 0; i < kIt; ++i) {
        vfloat4 o;
        o.x = (v[i].x - mean) * rcp;
        o.y = (v[i].y - mean) * rcp;
        o.z = (v[i].z - mean) * rcp;
        o.w = (v[i].w - mean) * rcp;
        __builtin_nontemporal_store(o, &ys[tid + i * kThreads]);
    }
    if (extra) {
        vfloat4 o;
        o.x = (ve.x - mean) * rcp;
        o.y = (ve.y - mean) * rcp;
        o.z = (ve.z - mean) * rcp;
        o.w = (ve.w - mean) * rcp;
        __builtin_nontemporal_store(o, &ys[kIt * kThreads + tid]);
    }
}

extern "C" void kernel_launch(void* const* d_in, const int* in_sizes, int n_in,
                              void* d_out, int out_size, void* d_ws, size_t ws_size,
                              hipStream_t stream) {
    (void)in_sizes; (void)n_in; (void)d_ws; (void)ws_size; (void)out_size;
    const float* x = reinterpret_cast<const float*>(d_in[0]);
    float* y = reinterpret_cast<float*>(d_out);
    whiten_r10<<<kSlices, kThreads, 0, stream>>>(x, y);
}